// Round 3
// baseline (148.430 us; speedup 1.0000x reference)
//
#include <hip/hip_runtime.h>

// NanoDet GFL loss (QFL + GIoU + DFL), single f32 scalar output.
// Pass 1: per-anchor math, 5 partial sums per block -> d_ws.
// Pass 2: deterministic single-block reduction + final normalization.

namespace {
constexpr int   kNumClasses = 80;
constexpr int   kRegMax     = 7;
constexpr float kEps        = 1e-6f;
constexpr int   kThreads    = 256;
constexpr int   kMaxBlocks  = 2048;
}

__device__ __forceinline__ float wave_reduce_sum(float v) {
#pragma unroll
  for (int off = 32; off > 0; off >>= 1) v += __shfl_down(v, off, 64);
  return v;
}

__global__ __launch_bounds__(kThreads) void nanodet_loss_main(
    const float* __restrict__ cls_score,     // [N,80]
    const float* __restrict__ bbox_pred,     // [N,32]
    const float* __restrict__ anchors,       // [N,4]
    const float* __restrict__ bbox_targets,  // [N,4]
    const float* __restrict__ label_weights, // [N]
    const float* __restrict__ strides,       // [N]
    const int*   __restrict__ labels,        // [N]
    float*       __restrict__ partials,      // [grid][5]
    int N)
{
  float s_qfl = 0.f, s_bbox = 0.f, s_dfl = 0.f, s_wt = 0.f, s_pos = 0.f;

  for (int n = blockIdx.x * kThreads + threadIdx.x; n < N;
       n += gridDim.x * kThreads) {
    const int  lab = labels[n];
    const bool pos = (unsigned)lab < (unsigned)kNumClasses;
    const float inv_s = 1.0f / strides[n];

    const float4 anc = reinterpret_cast<const float4*>(anchors)[n];
    const float cx = (anc.x + anc.z) * 0.5f * inv_s;
    const float cy = (anc.y + anc.w) * 0.5f * inv_s;

    const float4 tg = reinterpret_cast<const float4*>(bbox_targets)[n];
    const float tx0 = tg.x * inv_s, ty0 = tg.y * inv_s;
    const float tx1 = tg.z * inv_s, ty1 = tg.w * inv_s;

    // ---- bbox_pred row: 4 sides x 8 bins (all compile-time indexed) ----
    float xs[32];
#pragma unroll
    for (int i = 0; i < 8; ++i) {
      const float4 v =
          reinterpret_cast<const float4*>(bbox_pred + (size_t)n * 32)[i];
      xs[i * 4 + 0] = v.x; xs[i * 4 + 1] = v.y;
      xs[i * 4 + 2] = v.z; xs[i * 4 + 3] = v.w;
    }

    float corners[4], logZ[4];
#pragma unroll
    for (int k = 0; k < 4; ++k) {
      float m = xs[k * 8];
#pragma unroll
      for (int b = 1; b < 8; ++b) m = fmaxf(m, xs[k * 8 + b]);
      float Z = 0.f, E = 0.f;
#pragma unroll
      for (int b = 0; b < 8; ++b) {
        const float e = __expf(xs[k * 8 + b] - m);
        Z += e;
        E += (float)b * e;
      }
      corners[k] = E / Z;          // softmax expectation (integral)
      logZ[k]    = m + __logf(Z);  // for log_softmax in DFL
    }

    const float px0 = cx - corners[0], py0 = cy - corners[1];
    const float px1 = cx + corners[2], py1 = cy + corners[3];

    // ---- aligned IoU (for QFL target) + GIoU (for bbox loss) ----
    const float ov_w = fmaxf(fminf(px1, tx1) - fmaxf(px0, tx0), 0.f);
    const float ov_h = fmaxf(fminf(py1, ty1) - fmaxf(py0, ty0), 0.f);
    const float overlap = ov_w * ov_h;
    const float area_p = fmaxf(px1 - px0, 0.f) * fmaxf(py1 - py0, 0.f);
    const float area_t = fmaxf(tx1 - tx0, 0.f) * fmaxf(ty1 - ty0, 0.f);
    const float uni = area_p + area_t - overlap;
    const float iou = overlap / fmaxf(uni, kEps);
    const float score = pos ? iou : 0.f;

    const float uni_g = fmaxf(uni, kEps);
    const float iou_g = overlap / uni_g;
    const float en_w = fmaxf(fmaxf(px1, tx1) - fminf(px0, tx0), 0.f);
    const float en_h = fmaxf(fmaxf(py1, ty1) - fminf(py0, ty0), 0.f);
    const float enclose = fmaxf(en_w * en_h, kEps);
    const float giou = iou_g - (enclose - uni_g) / enclose;

    // ---- QFL over 80 classes + running max(sigmoid) ----
    const float* cr = cls_score + (size_t)n * kNumClasses;
    float max_sig = 0.f, qfl = 0.f;
    for (int c0 = 0; c0 < kNumClasses; c0 += 4) {
      const float4 xv = reinterpret_cast<const float4*>(cr)[c0 >> 2];
      const float xa[4] = {xv.x, xv.y, xv.z, xv.w};
#pragma unroll
      for (int j = 0; j < 4; ++j) {
        const float x   = xa[j];
        const float sig = 1.f / (1.f + __expf(-x));
        // bce(x, t) = max(x,0) - x*t + log1p(exp(-|x|))
        const float bce0 = fmaxf(x, 0.f) + log1pf(__expf(-fabsf(x)));
        const float dq   = score - sig;
        const float pos_loss = (bce0 - x * score) * dq * dq;
        const float neg_loss = bce0 * sig * sig;
        qfl += (pos && (c0 + j) == lab) ? pos_loss : neg_loss;
        max_sig = fmaxf(max_sig, sig);
      }
    }
    const float wt = pos ? max_sig : 0.f;

    // ---- DFL: gather-free linear-interp form ----
    // ce_l*wl + ce_r*wr  ==  sum_b max(0, 1-|d-b|) * (logZ - x[b])
    const float dist[4] = {cx - tx0, cy - ty0, tx1 - cx, ty1 - cy};
    float dfl = 0.f;
#pragma unroll
    for (int k = 0; k < 4; ++k) {
      const float d = fminf(fmaxf(dist[k], 0.f), (float)kRegMax - 0.01f);
#pragma unroll
      for (int b = 0; b < 8; ++b) {
        const float w = fmaxf(1.f - fabsf(d - (float)b), 0.f);
        dfl += w * (logZ[k] - xs[k * 8 + b]);
      }
    }

    s_qfl  += qfl * label_weights[n];
    s_bbox += (1.f - giou) * wt;
    s_dfl  += dfl * wt;
    s_wt   += wt;
    s_pos  += pos ? 1.f : 0.f;
  }

  // ---- deterministic block reduction (4 waves) ----
  __shared__ float red[4][5];
  float vals[5] = {s_qfl, s_bbox, s_dfl, s_wt, s_pos};
  const int lane = threadIdx.x & 63, wid = threadIdx.x >> 6;
#pragma unroll
  for (int k = 0; k < 5; ++k) {
    const float r = wave_reduce_sum(vals[k]);
    if (lane == 0) red[wid][k] = r;
  }
  __syncthreads();
  if (threadIdx.x < 5) {
    const int k = threadIdx.x;
    partials[(size_t)blockIdx.x * 5 + k] =
        red[0][k] + red[1][k] + red[2][k] + red[3][k];
  }
}

__global__ __launch_bounds__(kThreads) void nanodet_loss_final(
    const float* __restrict__ partials, int nblocks, float* __restrict__ out)
{
  float v[5] = {0.f, 0.f, 0.f, 0.f, 0.f};
  for (int i = threadIdx.x; i < nblocks; i += kThreads) {
#pragma unroll
    for (int k = 0; k < 5; ++k) v[k] += partials[(size_t)i * 5 + k];
  }
  __shared__ float red[4][5];
  const int lane = threadIdx.x & 63, wid = threadIdx.x >> 6;
#pragma unroll
  for (int k = 0; k < 5; ++k) {
    const float r = wave_reduce_sum(v[k]);
    if (lane == 0) red[wid][k] = r;
  }
  __syncthreads();
  if (threadIdx.x == 0) {
    const float S_qfl  = red[0][0] + red[1][0] + red[2][0] + red[3][0];
    const float S_bbox = red[0][1] + red[1][1] + red[2][1] + red[3][1];
    const float S_dfl  = red[0][2] + red[1][2] + red[2][2] + red[3][2];
    const float S_wt   = red[0][3] + red[1][3] + red[2][3] + red[3][3];
    const float S_pos  = red[0][4] + red[1][4] + red[2][4] + red[3][4];
    const float num_pos = fmaxf(S_pos, 1.0f);   // num_total_samples
    const float avg     = fmaxf(S_wt, kEps);    // avg_factor = sum(wt)
    // loss_qfl/num_pos + 2*S_bbox/avg + (0.25/4)*S_dfl/avg
    out[0] = S_qfl / num_pos + 2.0f * S_bbox / avg + 0.0625f * S_dfl / avg;
  }
}

extern "C" void kernel_launch(void* const* d_in, const int* in_sizes, int n_in,
                              void* d_out, int out_size, void* d_ws, size_t ws_size,
                              hipStream_t stream) {
  const float* cls_score     = (const float*)d_in[0];
  const float* bbox_pred     = (const float*)d_in[1];
  const float* anchors       = (const float*)d_in[2];
  const float* bbox_targets  = (const float*)d_in[3];
  const float* label_weights = (const float*)d_in[4];
  const float* strides       = (const float*)d_in[5];
  const int*   labels        = (const int*)d_in[6];
  const int N = in_sizes[4];  // label_weights is [N]

  float* partials = (float*)d_ws;

  int grid = (N + kThreads - 1) / kThreads;
  if (grid > kMaxBlocks) grid = kMaxBlocks;
  if (grid < 1) grid = 1;

  nanodet_loss_main<<<grid, kThreads, 0, stream>>>(
      cls_score, bbox_pred, anchors, bbox_targets, label_weights, strides,
      labels, partials, N);
  nanodet_loss_final<<<1, kThreads, 0, stream>>>(partials, grid, (float*)d_out);
}

// Round 4
// 58.714 us; speedup vs baseline: 2.5280x; 2.5280x over previous
//
#include <hip/hip_runtime.h>

// NanoDet GFL loss (QFL + GIoU + DFL), single f32 scalar output.
// R3: VALU-bound fix — hardware exp2/log2/rcp, single-exp sigmoid/BCE,
// fused softmax+DFL (xs dies inside the k-loop), hoisted positive-class
// correction. Target: HBM roofline (~226 MB -> ~36 us floor).

namespace {
constexpr int   kNumClasses = 80;
constexpr float kEps        = 1e-6f;
constexpr int   kThreads    = 256;
constexpr int   kMaxBlocks  = 2048;
constexpr float kLog2E      = 1.4426950408889634f;
constexpr float kLn2        = 0.6931471805599453f;
}

__device__ __forceinline__ float fexp2(float x) { return __builtin_amdgcn_exp2f(x); }
__device__ __forceinline__ float flog2(float x) { return __builtin_amdgcn_logf(x); }
__device__ __forceinline__ float frcp(float x)  { return __builtin_amdgcn_rcpf(x); }

__device__ __forceinline__ float wave_reduce_sum(float v) {
#pragma unroll
  for (int off = 32; off > 0; off >>= 1) v += __shfl_down(v, off, 64);
  return v;
}

__global__ __launch_bounds__(kThreads) void nanodet_loss_main(
    const float* __restrict__ cls_score,     // [N,80]
    const float* __restrict__ bbox_pred,     // [N,32]
    const float* __restrict__ anchors,       // [N,4]
    const float* __restrict__ bbox_targets,  // [N,4]
    const float* __restrict__ label_weights, // [N]
    const float* __restrict__ strides,       // [N]
    const int*   __restrict__ labels,        // [N]
    float*       __restrict__ partials,      // [grid][5]
    int N)
{
  float s_qfl = 0.f, s_bbox = 0.f, s_dfl = 0.f, s_wt = 0.f, s_pos = 0.f;

  for (int n = blockIdx.x * kThreads + threadIdx.x; n < N;
       n += gridDim.x * kThreads) {
    const int  lab = labels[n];
    const bool pos = (unsigned)lab < (unsigned)kNumClasses;
    const float inv_s = frcp(strides[n]);

    const float4 anc = reinterpret_cast<const float4*>(anchors)[n];
    const float cx = (anc.x + anc.z) * 0.5f * inv_s;
    const float cy = (anc.y + anc.w) * 0.5f * inv_s;

    const float4 tg = reinterpret_cast<const float4*>(bbox_targets)[n];
    const float tx0 = tg.x * inv_s, ty0 = tg.y * inv_s;
    const float tx1 = tg.z * inv_s, ty1 = tg.w * inv_s;

    // ---- fused Integral softmax + DFL inner term, per side k ----
    // dfl_k = logZ_k - sum_b max(0, 1-|d-b|) * x_b   (since wl+wr == 1)
    const float dist[4] = {cx - tx0, cy - ty0, tx1 - cx, ty1 - cy};
    float corners[4];
    float dfl = 0.f;
    const float* bp = bbox_pred + (size_t)n * 32;
#pragma unroll
    for (int k = 0; k < 4; ++k) {
      const float4 v0 = reinterpret_cast<const float4*>(bp)[k * 2 + 0];
      const float4 v1 = reinterpret_cast<const float4*>(bp)[k * 2 + 1];
      const float xk[8] = {v0.x, v0.y, v0.z, v0.w, v1.x, v1.y, v1.z, v1.w};
      float m = xk[0];
#pragma unroll
      for (int b = 1; b < 8; ++b) m = fmaxf(m, xk[b]);
      const float m2 = m * kLog2E;
      const float d  = fminf(fmaxf(dist[k], 0.f), 6.99f);
      float Z = 0.f, E = 0.f, W = 0.f;
#pragma unroll
      for (int b = 0; b < 8; ++b) {
        const float e = fexp2(__builtin_fmaf(xk[b], kLog2E, -m2));
        Z += e;
        E = __builtin_fmaf((float)b, e, E);
        const float w = fmaxf(1.f - fabsf(d - (float)b), 0.f);
        W = __builtin_fmaf(w, xk[b], W);
      }
      corners[k] = E * frcp(Z);
      dfl += __builtin_fmaf(kLn2, flog2(Z), m) - W;  // logZ_k - W_k
    }

    const float px0 = cx - corners[0], py0 = cy - corners[1];
    const float px1 = cx + corners[2], py1 = cy + corners[3];

    // ---- aligned IoU (QFL target) + GIoU (bbox loss) ----
    const float ov_w = fmaxf(fminf(px1, tx1) - fmaxf(px0, tx0), 0.f);
    const float ov_h = fmaxf(fminf(py1, ty1) - fmaxf(py0, ty0), 0.f);
    const float overlap = ov_w * ov_h;
    const float area_p = fmaxf(px1 - px0, 0.f) * fmaxf(py1 - py0, 0.f);
    const float area_t = fmaxf(tx1 - tx0, 0.f) * fmaxf(ty1 - ty0, 0.f);
    const float uni = area_p + area_t - overlap;
    const float iou = overlap * frcp(fmaxf(uni, kEps));
    const float score = pos ? iou : 0.f;

    const float uni_g = fmaxf(uni, kEps);
    const float iou_g = overlap * frcp(uni_g);
    const float en_w = fmaxf(fmaxf(px1, tx1) - fminf(px0, tx0), 0.f);
    const float en_h = fmaxf(fmaxf(py1, ty1) - fminf(py0, ty0), 0.f);
    const float enclose = fmaxf(en_w * en_h, kEps);
    const float giou = iou_g - (enclose - uni_g) * frcp(enclose);

    // ---- QFL over 80 classes: all-neg sum + hoisted positive correction ----
    // e = 2^(-|x|*log2e); sig = x>=0 ? 1/(1+e) : 1-1/(1+e)
    // bce(x,0) = max(x,0) + ln2*log2(1+e)
    const float* cr = cls_score + (size_t)n * kNumClasses;
    float max_sig = 0.f, qfl = 0.f;
    for (int c0 = 0; c0 < kNumClasses; c0 += 8) {
      const float4 xv0 = reinterpret_cast<const float4*>(cr)[(c0 >> 2) + 0];
      const float4 xv1 = reinterpret_cast<const float4*>(cr)[(c0 >> 2) + 1];
      const float xa[8] = {xv0.x, xv0.y, xv0.z, xv0.w,
                           xv1.x, xv1.y, xv1.z, xv1.w};
#pragma unroll
      for (int j = 0; j < 8; ++j) {
        const float x   = xa[j];
        const float e   = fexp2(-fabsf(x) * kLog2E);
        const float u   = 1.f + e;
        const float r   = frcp(u);
        const float sig = (x >= 0.f) ? r : 1.f - r;
        const float bce0 = fmaxf(x, 0.f) + kLn2 * flog2(u);
        qfl = __builtin_fmaf(bce0 * sig, sig, qfl);
        max_sig = fmaxf(max_sig, sig);
      }
    }
    if (pos) {
      const float x   = cr[lab];
      const float e   = fexp2(-fabsf(x) * kLog2E);
      const float u   = 1.f + e;
      const float r   = frcp(u);
      const float sig = (x >= 0.f) ? r : 1.f - r;
      const float bce0 = fmaxf(x, 0.f) + kLn2 * flog2(u);
      const float dq  = score - sig;
      qfl += (bce0 - x * score) * dq * dq - bce0 * sig * sig;
    }
    const float wt = pos ? max_sig : 0.f;

    s_qfl  = __builtin_fmaf(qfl, label_weights[n], s_qfl);
    s_bbox = __builtin_fmaf(1.f - giou, wt, s_bbox);
    s_dfl  = __builtin_fmaf(dfl, wt, s_dfl);
    s_wt  += wt;
    s_pos += pos ? 1.f : 0.f;
  }

  // ---- deterministic block reduction (4 waves) ----
  __shared__ float red[4][5];
  float vals[5] = {s_qfl, s_bbox, s_dfl, s_wt, s_pos};
  const int lane = threadIdx.x & 63, wid = threadIdx.x >> 6;
#pragma unroll
  for (int k = 0; k < 5; ++k) {
    const float r = wave_reduce_sum(vals[k]);
    if (lane == 0) red[wid][k] = r;
  }
  __syncthreads();
  if (threadIdx.x < 5) {
    const int k = threadIdx.x;
    partials[(size_t)blockIdx.x * 5 + k] =
        red[0][k] + red[1][k] + red[2][k] + red[3][k];
  }
}

__global__ __launch_bounds__(kThreads) void nanodet_loss_final(
    const float* __restrict__ partials, int nblocks, float* __restrict__ out)
{
  float v[5] = {0.f, 0.f, 0.f, 0.f, 0.f};
  for (int i = threadIdx.x; i < nblocks; i += kThreads) {
#pragma unroll
    for (int k = 0; k < 5; ++k) v[k] += partials[(size_t)i * 5 + k];
  }
  __shared__ float red[4][5];
  const int lane = threadIdx.x & 63, wid = threadIdx.x >> 6;
#pragma unroll
  for (int k = 0; k < 5; ++k) {
    const float r = wave_reduce_sum(v[k]);
    if (lane == 0) red[wid][k] = r;
  }
  __syncthreads();
  if (threadIdx.x == 0) {
    const float S_qfl  = red[0][0] + red[1][0] + red[2][0] + red[3][0];
    const float S_bbox = red[0][1] + red[1][1] + red[2][1] + red[3][1];
    const float S_dfl  = red[0][2] + red[1][2] + red[2][2] + red[3][2];
    const float S_wt   = red[0][3] + red[1][3] + red[2][3] + red[3][3];
    const float S_pos  = red[0][4] + red[1][4] + red[2][4] + red[3][4];
    const float num_pos = fmaxf(S_pos, 1.0f);   // num_total_samples
    const float avg     = fmaxf(S_wt, kEps);    // avg_factor = sum(wt)
    out[0] = S_qfl / num_pos + 2.0f * S_bbox / avg + 0.0625f * S_dfl / avg;
  }
}

extern "C" void kernel_launch(void* const* d_in, const int* in_sizes, int n_in,
                              void* d_out, int out_size, void* d_ws, size_t ws_size,
                              hipStream_t stream) {
  const float* cls_score     = (const float*)d_in[0];
  const float* bbox_pred     = (const float*)d_in[1];
  const float* anchors       = (const float*)d_in[2];
  const float* bbox_targets  = (const float*)d_in[3];
  const float* label_weights = (const float*)d_in[4];
  const float* strides       = (const float*)d_in[5];
  const int*   labels        = (const int*)d_in[6];
  const int N = in_sizes[4];  // label_weights is [N]

  float* partials = (float*)d_ws;

  int grid = (N + kThreads - 1) / kThreads;
  if (grid > kMaxBlocks) grid = kMaxBlocks;
  if (grid < 1) grid = 1;

  nanodet_loss_main<<<grid, kThreads, 0, stream>>>(
      cls_score, bbox_pred, anchors, bbox_targets, label_weights, strides,
      labels, partials, N);
  nanodet_loss_final<<<1, kThreads, 0, stream>>>(partials, grid, (float*)d_out);
}

// Round 5
// 52.100 us; speedup vs baseline: 2.8489x; 1.1269x over previous
//
#include <hip/hip_runtime.h>

// NanoDet GFL loss (QFL + GIoU + DFL), single f32 scalar output.
// R4 restructure: split into
//   A) streaming elementwise QFL-negative sum over cls_score (145 MB,
//      coalesced float4, x4 unrolled grid-stride)  -> the only heavy kernel
//   B) positives-only (~5%) kernel: rowmax (=> max_sig), QFL positive
//      correction, Integral+DFL, IoU/GIoU, wt sums
//   C) deterministic final reduction + normalization.

namespace {
constexpr int   kNumClasses = 80;
constexpr int   kF4PerRow   = kNumClasses / 4;   // 20
constexpr float kEps        = 1e-6f;
constexpr int   kThreads    = 256;
constexpr int   kMaxBlocks  = 2048;
constexpr float kLog2E      = 1.4426950408889634f;
constexpr float kLn2        = 0.6931471805599453f;
}

__device__ __forceinline__ float fexp2(float x) { return __builtin_amdgcn_exp2f(x); }
__device__ __forceinline__ float flog2(float x) { return __builtin_amdgcn_logf(x); }
__device__ __forceinline__ float frcp(float x)  { return __builtin_amdgcn_rcpf(x); }

__device__ __forceinline__ float wave_reduce_sum(float v) {
#pragma unroll
  for (int off = 32; off > 0; off >>= 1) v += __shfl_down(v, off, 64);
  return v;
}

// bce(x,0) * sigmoid(x)^2 for one logit
__device__ __forceinline__ float neg_term(float x) {
  const float e   = fexp2(-fabsf(x) * kLog2E);
  const float u   = 1.f + e;
  const float r   = frcp(u);
  const float sig = (x >= 0.f) ? r : 1.f - r;
  const float bce0 = fmaxf(x, 0.f) + kLn2 * flog2(u);
  return bce0 * sig * sig;
}

__device__ __forceinline__ float neg_term4(float4 v) {
  return neg_term(v.x) + neg_term(v.y) + neg_term(v.z) + neg_term(v.w);
}

// ---------------- Kernel A: streaming negative-QFL sum ----------------
__global__ __launch_bounds__(kThreads) void qfl_neg_kernel(
    const float* __restrict__ cls_score,     // [N*80] flat
    const float* __restrict__ label_weights, // [N]
    float*       __restrict__ partialsA,     // [gridA]
    int M4)                                  // N*20 float4s
{
  const float4* cs = reinterpret_cast<const float4*>(cls_score);
  const int nth = gridDim.x * blockDim.x;
  int i = blockIdx.x * blockDim.x + threadIdx.x;
  float acc = 0.f;

  for (; i + 3 * nth < M4; i += 4 * nth) {
    const float4 v0 = cs[i];
    const float4 v1 = cs[i + nth];
    const float4 v2 = cs[i + 2 * nth];
    const float4 v3 = cs[i + 3 * nth];
    const float w0 = label_weights[i / kF4PerRow];
    const float w1 = label_weights[(i + nth) / kF4PerRow];
    const float w2 = label_weights[(i + 2 * nth) / kF4PerRow];
    const float w3 = label_weights[(i + 3 * nth) / kF4PerRow];
    acc = __builtin_fmaf(neg_term4(v0), w0, acc);
    acc = __builtin_fmaf(neg_term4(v1), w1, acc);
    acc = __builtin_fmaf(neg_term4(v2), w2, acc);
    acc = __builtin_fmaf(neg_term4(v3), w3, acc);
  }
  for (; i < M4; i += nth)
    acc = __builtin_fmaf(neg_term4(cs[i]), label_weights[i / kF4PerRow], acc);

  __shared__ float red[4];
  const int lane = threadIdx.x & 63, wid = threadIdx.x >> 6;
  const float r = wave_reduce_sum(acc);
  if (lane == 0) red[wid] = r;
  __syncthreads();
  if (threadIdx.x == 0)
    partialsA[blockIdx.x] = red[0] + red[1] + red[2] + red[3];
}

// ---------------- Kernel B: positives-only terms ----------------
__global__ __launch_bounds__(kThreads) void pos_kernel(
    const float* __restrict__ cls_score,     // [N,80]
    const float* __restrict__ bbox_pred,     // [N,32]
    const float* __restrict__ anchors,       // [N,4]
    const float* __restrict__ bbox_targets,  // [N,4]
    const float* __restrict__ label_weights, // [N]
    const float* __restrict__ strides,       // [N]
    const int*   __restrict__ labels,        // [N]
    float*       __restrict__ partialsB,     // [gridB][5]
    int N)
{
  float s_corr = 0.f, s_bbox = 0.f, s_dfl = 0.f, s_wt = 0.f, s_pos = 0.f;

  for (int n = blockIdx.x * kThreads + threadIdx.x; n < N;
       n += gridDim.x * kThreads) {
    const int lab = labels[n];
    if ((unsigned)lab >= (unsigned)kNumClasses) continue;  // negatives: nothing

    const float inv_s = frcp(strides[n]);
    const float lw = label_weights[n];

    const float4 anc = reinterpret_cast<const float4*>(anchors)[n];
    const float cx = (anc.x + anc.z) * 0.5f * inv_s;
    const float cy = (anc.y + anc.w) * 0.5f * inv_s;

    const float4 tg = reinterpret_cast<const float4*>(bbox_targets)[n];
    const float tx0 = tg.x * inv_s, ty0 = tg.y * inv_s;
    const float tx1 = tg.z * inv_s, ty1 = tg.w * inv_s;

    // ---- row max of cls logits (max sigmoid = sigmoid(max x)) ----
    const float* cr = cls_score + (size_t)n * kNumClasses;
    const float4* cr4 = reinterpret_cast<const float4*>(cr);
    float rm = -3.4e38f;
#pragma unroll
    for (int i = 0; i < kF4PerRow; ++i) {
      const float4 v = cr4[i];
      rm = fmaxf(rm, fmaxf(fmaxf(v.x, v.y), fmaxf(v.z, v.w)));
    }
    const float em  = fexp2(-fabsf(rm) * kLog2E);
    const float rmr = frcp(1.f + em);
    const float max_sig = (rm >= 0.f) ? rmr : 1.f - rmr;  // == wt

    // ---- fused Integral softmax + DFL, per side k ----
    const float dist[4] = {cx - tx0, cy - ty0, tx1 - cx, ty1 - cy};
    float corners[4];
    float dfl = 0.f;
    const float* bp = bbox_pred + (size_t)n * 32;
#pragma unroll
    for (int k = 0; k < 4; ++k) {
      const float4 v0 = reinterpret_cast<const float4*>(bp)[k * 2 + 0];
      const float4 v1 = reinterpret_cast<const float4*>(bp)[k * 2 + 1];
      const float xk[8] = {v0.x, v0.y, v0.z, v0.w, v1.x, v1.y, v1.z, v1.w};
      float m = xk[0];
#pragma unroll
      for (int b = 1; b < 8; ++b) m = fmaxf(m, xk[b]);
      const float m2 = m * kLog2E;
      const float d  = fminf(fmaxf(dist[k], 0.f), 6.99f);
      float Z = 0.f, E = 0.f, W = 0.f;
#pragma unroll
      for (int b = 0; b < 8; ++b) {
        const float e = fexp2(__builtin_fmaf(xk[b], kLog2E, -m2));
        Z += e;
        E = __builtin_fmaf((float)b, e, E);
        const float w = fmaxf(1.f - fabsf(d - (float)b), 0.f);
        W = __builtin_fmaf(w, xk[b], W);
      }
      corners[k] = E * frcp(Z);
      dfl += __builtin_fmaf(kLn2, flog2(Z), m) - W;  // logZ_k - W_k
    }

    const float px0 = cx - corners[0], py0 = cy - corners[1];
    const float px1 = cx + corners[2], py1 = cy + corners[3];

    // ---- aligned IoU (QFL target) + GIoU ----
    const float ov_w = fmaxf(fminf(px1, tx1) - fmaxf(px0, tx0), 0.f);
    const float ov_h = fmaxf(fminf(py1, ty1) - fmaxf(py0, ty0), 0.f);
    const float overlap = ov_w * ov_h;
    const float area_p = fmaxf(px1 - px0, 0.f) * fmaxf(py1 - py0, 0.f);
    const float area_t = fmaxf(tx1 - tx0, 0.f) * fmaxf(ty1 - ty0, 0.f);
    const float uni = area_p + area_t - overlap;
    const float score = overlap * frcp(fmaxf(uni, kEps));  // iou

    const float uni_g = fmaxf(uni, kEps);
    const float iou_g = overlap * frcp(uni_g);
    const float en_w = fmaxf(fmaxf(px1, tx1) - fminf(px0, tx0), 0.f);
    const float en_h = fmaxf(fmaxf(py1, ty1) - fminf(py0, ty0), 0.f);
    const float enclose = fmaxf(en_w * en_h, kEps);
    const float giou = iou_g - (enclose - uni_g) * frcp(enclose);

    // ---- QFL positive correction at class `lab` ----
    const float x    = cr[lab];
    const float e    = fexp2(-fabsf(x) * kLog2E);
    const float u    = 1.f + e;
    const float r    = frcp(u);
    const float sig  = (x >= 0.f) ? r : 1.f - r;
    const float bce0 = fmaxf(x, 0.f) + kLn2 * flog2(u);
    const float dq   = score - sig;
    const float corr = (bce0 - x * score) * dq * dq - bce0 * sig * sig;

    s_corr = __builtin_fmaf(corr, lw, s_corr);
    s_bbox = __builtin_fmaf(1.f - giou, max_sig, s_bbox);
    s_dfl  = __builtin_fmaf(dfl, max_sig, s_dfl);
    s_wt  += max_sig;
    s_pos += 1.f;
  }

  __shared__ float red[4][5];
  float vals[5] = {s_corr, s_bbox, s_dfl, s_wt, s_pos};
  const int lane = threadIdx.x & 63, wid = threadIdx.x >> 6;
#pragma unroll
  for (int k = 0; k < 5; ++k) {
    const float r = wave_reduce_sum(vals[k]);
    if (lane == 0) red[wid][k] = r;
  }
  __syncthreads();
  if (threadIdx.x < 5) {
    const int k = threadIdx.x;
    partialsB[(size_t)blockIdx.x * 5 + k] =
        red[0][k] + red[1][k] + red[2][k] + red[3][k];
  }
}

// ---------------- Kernel C: final reduction ----------------
__global__ __launch_bounds__(kThreads) void final_kernel(
    const float* __restrict__ partialsA, int nA,
    const float* __restrict__ partialsB, int nB,
    float* __restrict__ out)
{
  float vA = 0.f;
  for (int i = threadIdx.x; i < nA; i += kThreads) vA += partialsA[i];
  float v[5] = {0.f, 0.f, 0.f, 0.f, 0.f};
  for (int i = threadIdx.x; i < nB; i += kThreads) {
#pragma unroll
    for (int k = 0; k < 5; ++k) v[k] += partialsB[(size_t)i * 5 + k];
  }
  __shared__ float red[4][6];
  const int lane = threadIdx.x & 63, wid = threadIdx.x >> 6;
  {
    const float r = wave_reduce_sum(vA);
    if (lane == 0) red[wid][5] = r;
  }
#pragma unroll
  for (int k = 0; k < 5; ++k) {
    const float r = wave_reduce_sum(v[k]);
    if (lane == 0) red[wid][k] = r;
  }
  __syncthreads();
  if (threadIdx.x == 0) {
    const float S_neg  = red[0][5] + red[1][5] + red[2][5] + red[3][5];
    const float S_corr = red[0][0] + red[1][0] + red[2][0] + red[3][0];
    const float S_bbox = red[0][1] + red[1][1] + red[2][1] + red[3][1];
    const float S_dfl  = red[0][2] + red[1][2] + red[2][2] + red[3][2];
    const float S_wt   = red[0][3] + red[1][3] + red[2][3] + red[3][3];
    const float S_pos  = red[0][4] + red[1][4] + red[2][4] + red[3][4];
    const float num_pos = fmaxf(S_pos, 1.0f);   // num_total_samples
    const float avg     = fmaxf(S_wt, kEps);    // avg_factor = sum(wt)
    out[0] = (S_neg + S_corr) / num_pos
           + 2.0f * S_bbox / avg + 0.0625f * S_dfl / avg;
  }
}

extern "C" void kernel_launch(void* const* d_in, const int* in_sizes, int n_in,
                              void* d_out, int out_size, void* d_ws, size_t ws_size,
                              hipStream_t stream) {
  const float* cls_score     = (const float*)d_in[0];
  const float* bbox_pred     = (const float*)d_in[1];
  const float* anchors       = (const float*)d_in[2];
  const float* bbox_targets  = (const float*)d_in[3];
  const float* label_weights = (const float*)d_in[4];
  const float* strides       = (const float*)d_in[5];
  const int*   labels        = (const int*)d_in[6];
  const int N  = in_sizes[4];      // label_weights is [N]
  const int M4 = N * kF4PerRow;    // float4 count of cls_score

  float* partialsA = (float*)d_ws;                 // [kMaxBlocks]
  float* partialsB = (float*)d_ws + kMaxBlocks;    // [kMaxBlocks][5]

  int gridA = (M4 + kThreads - 1) / kThreads;
  if (gridA > kMaxBlocks) gridA = kMaxBlocks;
  if (gridA < 1) gridA = 1;
  int gridB = (N + kThreads - 1) / kThreads;
  if (gridB > kMaxBlocks) gridB = kMaxBlocks;
  if (gridB < 1) gridB = 1;

  qfl_neg_kernel<<<gridA, kThreads, 0, stream>>>(
      cls_score, label_weights, partialsA, M4);
  pos_kernel<<<gridB, kThreads, 0, stream>>>(
      cls_score, bbox_pred, anchors, bbox_targets, label_weights, strides,
      labels, partialsB, N);
  final_kernel<<<1, kThreads, 0, stream>>>(
      partialsA, gridA, partialsB, gridB, (float*)d_out);
}